// Round 1
// baseline (19409.447 us; speedup 1.0000x reference)
//
#include <hip/hip_runtime.h>
#include <hip/hip_bf16.h>

// Jordan RNN restructured:
//   Wc = Wyh @ Wout  [H,H]
//   pre[b,t,:] = emb@Whx^T + bhx + byh + (t==0 ? last_logits@Wyh^T : Wyh@bout)
//   scan: h_t = tanh(pre_t + h_{t-1} @ Wc^T)     (per-batch independent!)
//   y_t  = h_t @ Wout^T + bout                    (time-parallel epilogue GEMM)
// Buffers: pre/h live in d_out[0:B*T*H] (fp32, in-place through all phases);
//          d_ws holds ~2.7MB of prepped weights (bf16 MFMA-fragment layout).

#define NB 64
#define NT 2048
#define ND 512
#define NH 512
#define NO 512
#define TH (NT * NH)

typedef float f32x4 __attribute__((ext_vector_type(4)));
typedef __bf16 bf16x8 __attribute__((ext_vector_type(8)));
typedef unsigned short u16x8 __attribute__((ext_vector_type(8)));

__device__ __forceinline__ unsigned short f2bf(float x) {
  unsigned u = __builtin_bit_cast(unsigned, x);
  u += 0x7FFFu + ((u >> 16) & 1u);               // RNE
  return (unsigned short)(u >> 16);
}
__device__ __forceinline__ bf16x8 ld_frag(const unsigned short* p) {
  u16x8 r = *(const u16x8*)p;
  return __builtin_bit_cast(bf16x8, r);
}

// ---------------- prep kernels ----------------

// bias_t0[j] = bhx[j]+byh[j];  bias_t[j] = bhx[j]+byh[j] + sum_o Wyh[j,o]*bout[o]
__global__ void k_bias(const float* __restrict__ Wyh, const float* __restrict__ bout,
                       const float* __restrict__ bhx, const float* __restrict__ byh,
                       float* bias_t0, float* bias_t) {
  int j = threadIdx.x;
  const float* row = Wyh + j * NO;
  float acc = 0.f;
  for (int o = 0; o < NO; ++o) acc += row[o] * bout[o];
  bias_t0[j] = bhx[j] + byh[j];
  bias_t[j]  = bhx[j] + byh[j] + acc;
}

// z0[b,j] = sum_o last_logits[b,o] * Wyh[j,o]
__global__ void k_z0(const float* __restrict__ ll, const float* __restrict__ Wyh,
                     float* z0) {
  int b = blockIdx.x, j = threadIdx.x;
  const float* row = Wyh + j * NO;
  const float* lr = ll + b * NO;
  float acc = 0.f;
  for (int o = 0; o < NO; ++o) acc += lr[o] * row[o];
  z0[b * NH + j] = acc;
}

// Wc[j,k] = sum_o Wyh[j,o] * Wout[o,k]
__global__ void k_wc(const float* __restrict__ Wyh, const float* __restrict__ Wout,
                     float* Wc) {
  int j = blockIdx.x, k = threadIdx.x;
  float acc = 0.f;
  for (int o = 0; o < NO; ++o) acc += Wyh[j * NO + o] * Wout[o * NH + k];
  Wc[j * NH + k] = acc;
}

// Build MFMA B-operand fragments for Bm = src^T (src is [N=512 rows][K=512 cols]).
// Bm[k][n] = src[n*512 + k].  Fragment for 16x16x32: lane l holds
// B[kt*32 + (l>>4)*8 + i][nt*16 + (l&15)], i=0..7.  dst index ((kt*32+nt)*64+l)*8+i.
__global__ void k_frag(const float* __restrict__ src, unsigned short* __restrict__ dst) {
  int gid = blockIdx.x * 256 + threadIdx.x;  // 32768 total
  int lane = gid & 63, tidx = gid >> 6;
  int nt = tidx & 31, kt = tidx >> 5;
  const float* s = src + (size_t)(nt * 16 + (lane & 15)) * 512 + kt * 32 + (lane >> 4) * 8;
  unsigned short* d = dst + (size_t)gid * 8;
#pragma unroll
  for (int i = 0; i < 8; ++i) d[i] = f2bf(s[i]);
}

// ---------------- big GEMM (P1 and P3) ----------------
// out[row, col] = sum_k A[row,k]*Bm[k,col] + bias;  A fp32 [131072 x 512], B in frag layout.
// mode 0 (P1): bias = (t==0 ? bias_t0[col]+z0[b,col] : bias_t[col])
// mode 1 (P3): bias = bout[col]; in-place (A == out); rows with t==T-1 also -> last[]
__global__ __launch_bounds__(512) void k_gemm(
    const float* __restrict__ A, const unsigned short* __restrict__ fragB,
    float* __restrict__ out, int mode, const float* __restrict__ bias_t0,
    const float* __restrict__ bias_t, const float* __restrict__ z0,
    const float* __restrict__ bout, float* __restrict__ last) {
  __shared__ __align__(16) unsigned short a_lds[64 * 512];  // 64KB, XOR-swizzled bf16
  int tid = threadIdx.x;
  long bt0 = (long)blockIdx.x * 64;

  // stage A tile [64 x 512] fp32 -> bf16 LDS (fully staged before any write: in-place safe)
#pragma unroll
  for (int it = 0; it < 16; ++it) {
    int chunk = it * 512 + tid;
    int r = chunk >> 7, c4 = chunk & 127;
    float4 v = ((const float4*)A)[(bt0 + r) * 128 + c4];
    int idx = (r * 512 + c4 * 4) ^ ((r & 7) << 3);
    unsigned short* p = &a_lds[idx];
    p[0] = f2bf(v.x); p[1] = f2bf(v.y); p[2] = f2bf(v.z); p[3] = f2bf(v.w);
  }
  __syncthreads();

  int wave = tid >> 6, lane = tid & 63;
  int r0 = (wave & 3) * 16, c0 = (wave >> 2) * 256;
  f32x4 acc[16];
#pragma unroll
  for (int n = 0; n < 16; ++n) acc[n] = (f32x4){0.f, 0.f, 0.f, 0.f};
  int arow = r0 + (lane & 15);

  for (int kt = 0; kt < 16; ++kt) {
    int aidx = (arow * 512 + kt * 32 + (lane >> 4) * 8) ^ ((arow & 7) << 3);
    bf16x8 a = ld_frag(&a_lds[aidx]);
    const unsigned short* bp = fragB + ((size_t)(kt * 32 + (c0 >> 4)) * 64 + lane) * 8;
#pragma unroll
    for (int n = 0; n < 16; ++n) {
      bf16x8 b = ld_frag(bp + (size_t)n * 512);
      acc[n] = __builtin_amdgcn_mfma_f32_16x16x32_bf16(a, b, acc[n], 0, 0, 0);
    }
  }

#pragma unroll
  for (int n = 0; n < 16; ++n) {
    int col = c0 + n * 16 + (lane & 15);
#pragma unroll
    for (int reg = 0; reg < 4; ++reg) {
      long row = bt0 + r0 + (lane >> 4) * 4 + reg;
      float v = acc[n][reg];
      if (mode == 0) {
        int t = (int)(row & (NT - 1));
        long b = row >> 11;
        v += (t == 0) ? (bias_t0[col] + z0[b * NH + col]) : bias_t[col];
      } else {
        v += bout[col];
      }
      out[row * 512 + col] = v;
      if (mode == 1 && ((row & (NT - 1)) == NT - 1)) last[(row >> 11) * 512 + col] = v;
    }
  }
}

// ---------------- sequential scan ----------------
// grid 4 x 512 threads; WG w owns batches [16w, 16w+16). No inter-WG sync.
// h state: LDS bf16 [2][16][512], XOR-swizzled; fp32 h written back to buf for P3.
__global__ __launch_bounds__(512) void k_scan(float* __restrict__ buf,
                                              const unsigned short* __restrict__ fragWc) {
  __shared__ __align__(16) unsigned short h_lds[2][16 * 512];  // 32KB
  int tid = threadIdx.x;
  int b0 = blockIdx.x * 16;

  // t = 0: h0 = tanh(pre0)
  for (int i = 0; i < 16; ++i) {
    size_t g = (size_t)(b0 + i) * TH + tid;
    float h = tanhf(buf[g]);
    buf[g] = h;
    h_lds[0][(i * 512 + tid) ^ ((i & 7) << 3)] = f2bf(h);
  }
  __syncthreads();

  int wave = tid >> 6, lane = tid & 63;
  int c0 = wave * 64;
  int bb = lane >> 4;       // 0..3
  int arow = lane & 15;     // batch row for A fragment

  // preload pre(t=1) into regs (acc layout)
  float pre[16];
#pragma unroll
  for (int n = 0; n < 4; ++n)
#pragma unroll
    for (int reg = 0; reg < 4; ++reg) {
      int b = bb * 4 + reg, j = c0 + n * 16 + (lane & 15);
      pre[n * 4 + reg] = buf[(size_t)(b0 + b) * TH + (size_t)512 + j];
    }

#pragma unroll 1
  for (int t = 1; t < NT; ++t) {
    f32x4 acc[4];
#pragma unroll
    for (int n = 0; n < 4; ++n)
#pragma unroll
      for (int reg = 0; reg < 4; ++reg) acc[n][reg] = pre[n * 4 + reg];

    // prefetch pre(t+1); latency hides under MFMA phase
    if (t < NT - 1) {
#pragma unroll
      for (int n = 0; n < 4; ++n)
#pragma unroll
        for (int reg = 0; reg < 4; ++reg) {
          int b = bb * 4 + reg, j = c0 + n * 16 + (lane & 15);
          pre[n * 4 + reg] = buf[(size_t)(b0 + b) * TH + (size_t)(t + 1) * 512 + j];
        }
    }

    const unsigned short* hsrc = h_lds[(t - 1) & 1];
    for (int kt = 0; kt < 16; ++kt) {
      int aidx = (arow * 512 + kt * 32 + bb * 8) ^ ((arow & 7) << 3);
      bf16x8 a = ld_frag(&hsrc[aidx]);
      const unsigned short* bp = fragWc + ((size_t)(kt * 32 + wave * 4) * 64 + lane) * 8;
#pragma unroll
      for (int n = 0; n < 4; ++n) {
        bf16x8 b = ld_frag(bp + (size_t)n * 512);
        acc[n] = __builtin_amdgcn_mfma_f32_16x16x32_bf16(a, b, acc[n], 0, 0, 0);
      }
    }

    unsigned short* hdst = h_lds[t & 1];
#pragma unroll
    for (int n = 0; n < 4; ++n)
#pragma unroll
      for (int reg = 0; reg < 4; ++reg) {
        int b = bb * 4 + reg, j = c0 + n * 16 + (lane & 15);
        float h = tanhf(acc[n][reg]);
        buf[(size_t)(b0 + b) * TH + (size_t)t * 512 + j] = h;  // fp32 h for P3
        hdst[(b * 512 + j) ^ ((b & 7) << 3)] = f2bf(h);
      }
    __syncthreads();
  }
}

// ---------------- launch ----------------
extern "C" void kernel_launch(void* const* d_in, const int* in_sizes, int n_in,
                              void* d_out, int out_size, void* d_ws, size_t ws_size,
                              hipStream_t stream) {
  const float* emb  = (const float*)d_in[0];
  const float* ll   = (const float*)d_in[1];
  const float* Whx  = (const float*)d_in[2];
  const float* bhx  = (const float*)d_in[3];
  const float* Wyh  = (const float*)d_in[4];
  const float* byh  = (const float*)d_in[5];
  const float* Wout = (const float*)d_in[6];
  const float* bout = (const float*)d_in[7];

  float* buf  = (float*)d_out;                       // [B*T, 512] pre -> h -> y (in place)
  float* last = buf + (size_t)NB * NT * NO;          // [B, O] tail

  char* ws = (char*)d_ws;                            // needs ~2.7 MB
  unsigned short* fragWhx  = (unsigned short*)ws;                       // 512KB
  unsigned short* fragWc   = (unsigned short*)(ws + (512 * 512 * 2));   // 512KB
  unsigned short* fragWout = (unsigned short*)(ws + 2 * (512 * 512 * 2)); // 512KB
  float* z0      = (float*)(ws + 3 * (512 * 512 * 2));                 // 128KB
  float* bias_t0 = z0 + NB * NH;                                       // 2KB
  float* bias_t  = bias_t0 + NH;                                       // 2KB
  float* Wc_f32  = bias_t + NH;                                        // 1MB

  k_bias<<<1, 512, 0, stream>>>(Wyh, bout, bhx, byh, bias_t0, bias_t);
  k_z0<<<64, 512, 0, stream>>>(ll, Wyh, z0);
  k_wc<<<512, 512, 0, stream>>>(Wyh, Wout, Wc_f32);
  k_frag<<<128, 256, 0, stream>>>(Whx, fragWhx);     // Bm[d][j] = Whx[j][d]
  k_frag<<<128, 256, 0, stream>>>(Wc_f32, fragWc);   // Bm[k][j] = Wc[j][k]
  k_frag<<<128, 256, 0, stream>>>(Wout, fragWout);   // Bm[k][o] = Wout[o][k]

  // P1: pre = emb @ Whx^T + biases (t==0 rows get z0)
  k_gemm<<<2048, 512, 0, stream>>>(emb, fragWhx, buf, 0, bias_t0, bias_t, z0, bout, last);
  // P2: sequential scan, h in place over pre
  k_scan<<<4, 512, 0, stream>>>(buf, fragWc);
  // P3: y = h @ Wout^T + bout, in place over h; also fills `last`
  k_gemm<<<2048, 512, 0, stream>>>(buf, fragWout, buf, 1, bias_t0, bias_t, z0, bout, last);
}

// Round 2
// 17631.226 us; speedup vs baseline: 1.1009x; 1.1009x over previous
//
#include <hip/hip_runtime.h>
#include <hip/hip_bf16.h>

// Jordan RNN restructured:
//   Wc = Wyh @ Wout  [H,H]
//   pre[b,t,:] = emb@Whx^T + bhx + byh + (t==0 ? last_logits@Wyh^T : Wyh@bout)
//   scan: h_t = tanh(pre_t + h_{t-1} @ Wc^T)     (per-batch independent!)
//   y_t  = h_t @ Wout^T + bout                    (time-parallel epilogue GEMM)
// Buffers: pre/h live in d_out[0:B*T*H] (in-place through all phases; h is
// stored bf16 in the low half of each fp32 row); d_ws holds ~2.7MB of prepped
// weights (bf16 MFMA-fragment layout).

#define NB 64
#define NT 2048
#define ND 512
#define NH 512
#define NO 512
#define TH (NT * NH)

typedef float f32x4 __attribute__((ext_vector_type(4)));
typedef __bf16 bf16x8 __attribute__((ext_vector_type(8)));
typedef unsigned short u16x8 __attribute__((ext_vector_type(8)));

__device__ __forceinline__ unsigned short f2bf(float x) {
  unsigned u = __builtin_bit_cast(unsigned, x);
  u += 0x7FFFu + ((u >> 16) & 1u);               // RNE
  return (unsigned short)(u >> 16);
}
__device__ __forceinline__ bf16x8 ld_frag(const unsigned short* p) {
  u16x8 r = *(const u16x8*)p;
  return __builtin_bit_cast(bf16x8, r);
}
// tanh via hardware exp2/rcp: tanh(|x|) = 1 - 2/(exp2(2*log2e*|x|)+1), sign restored.
// abs err ~1e-6; inf-safe for large |x| (rcp(inf)=0 -> 1).
__device__ __forceinline__ float fast_tanh(float x) {
  float ax = __builtin_fabsf(x);
  float e = __builtin_amdgcn_exp2f(ax * 2.8853900817779268f);  // e^(2|x|)
  float r = 1.0f - 2.0f * __builtin_amdgcn_rcpf(e + 1.0f);
  return __builtin_copysignf(r, x);
}

// ---------------- prep kernels ----------------

__global__ void k_bias(const float* __restrict__ Wyh, const float* __restrict__ bout,
                       const float* __restrict__ bhx, const float* __restrict__ byh,
                       float* bias_t0, float* bias_t) {
  int j = threadIdx.x;
  const float* row = Wyh + j * NO;
  float acc = 0.f;
  for (int o = 0; o < NO; ++o) acc += row[o] * bout[o];
  bias_t0[j] = bhx[j] + byh[j];
  bias_t[j]  = bhx[j] + byh[j] + acc;
}

__global__ void k_z0(const float* __restrict__ ll, const float* __restrict__ Wyh,
                     float* z0) {
  int b = blockIdx.x, j = threadIdx.x;
  const float* row = Wyh + j * NO;
  const float* lr = ll + b * NO;
  float acc = 0.f;
  for (int o = 0; o < NO; ++o) acc += lr[o] * row[o];
  z0[b * NH + j] = acc;
}

__global__ void k_wc(const float* __restrict__ Wyh, const float* __restrict__ Wout,
                     float* Wc) {
  int j = blockIdx.x, k = threadIdx.x;
  float acc = 0.f;
  for (int o = 0; o < NO; ++o) acc += Wyh[j * NO + o] * Wout[o * NH + k];
  Wc[j * NH + k] = acc;
}

// Build MFMA B-operand fragments for Bm = src^T (src is [N=512 rows][K=512 cols]).
// Fragment for 16x16x32: lane l holds B[kt*32 + (l>>4)*8 + i][nt*16 + (l&15)], i=0..7.
__global__ void k_frag(const float* __restrict__ src, unsigned short* __restrict__ dst) {
  int gid = blockIdx.x * 256 + threadIdx.x;  // 32768 total
  int lane = gid & 63, tidx = gid >> 6;
  int nt = tidx & 31, kt = tidx >> 5;
  const float* s = src + (size_t)(nt * 16 + (lane & 15)) * 512 + kt * 32 + (lane >> 4) * 8;
  unsigned short* d = dst + (size_t)gid * 8;
#pragma unroll
  for (int i = 0; i < 8; ++i) d[i] = f2bf(s[i]);
}

// ---------------- big GEMM (P1 and P3) ----------------
// MODE 0 (P1): A fp32 (emb); bias = (t==0 ? bias_t0+z0 : bias_t)
// MODE 1 (P3): A bf16 packed in low half of each fp32 row (h from scan);
//              bias = bout; in-place (A aliases out); t==T-1 rows -> last[]
template <int MODE>
__global__ __launch_bounds__(512) void k_gemm(
    const void* __restrict__ Ain, const unsigned short* __restrict__ fragB,
    float* __restrict__ out, const float* __restrict__ bias_t0,
    const float* __restrict__ bias_t, const float* __restrict__ z0,
    const float* __restrict__ bout, float* __restrict__ last) {
  __shared__ __align__(16) unsigned short a_lds[64 * 512];  // 64KB, XOR-swizzled bf16
  int tid = threadIdx.x;
  long bt0 = (long)blockIdx.x * 64;

  if (MODE == 0) {
    const float* A = (const float*)Ain;
#pragma unroll
    for (int it = 0; it < 16; ++it) {
      int chunk = it * 512 + tid;
      int r = chunk >> 7, c4 = chunk & 127;
      float4 v = ((const float4*)A)[(bt0 + r) * 128 + c4];
      int idx = (r * 512 + c4 * 4) ^ ((r & 7) << 3);
      unsigned short* p = &a_lds[idx];
      p[0] = f2bf(v.x); p[1] = f2bf(v.y); p[2] = f2bf(v.z); p[3] = f2bf(v.w);
    }
  } else {
    const unsigned short* A = (const unsigned short*)Ain;
#pragma unroll
    for (int it = 0; it < 8; ++it) {
      int chunk = it * 512 + tid;           // 4096 chunks of 8 u16
      int r = chunk >> 6, c8 = chunk & 63;
      u16x8 v = *(const u16x8*)(A + (size_t)(bt0 + r) * 1024 + c8 * 8);
      int idx = (r * 512 + c8 * 8) ^ ((r & 7) << 3);
      *(u16x8*)&a_lds[idx] = v;
    }
  }
  __syncthreads();

  int wave = tid >> 6, lane = tid & 63;
  int r0 = (wave & 3) * 16, c0 = (wave >> 2) * 256;
  f32x4 acc[16];
#pragma unroll
  for (int n = 0; n < 16; ++n) acc[n] = (f32x4){0.f, 0.f, 0.f, 0.f};
  int arow = r0 + (lane & 15);

  for (int kt = 0; kt < 16; ++kt) {
    int aidx = (arow * 512 + kt * 32 + (lane >> 4) * 8) ^ ((arow & 7) << 3);
    bf16x8 a = ld_frag(&a_lds[aidx]);
    const unsigned short* bp = fragB + ((size_t)(kt * 32 + (c0 >> 4)) * 64 + lane) * 8;
#pragma unroll
    for (int n = 0; n < 16; ++n) {
      bf16x8 b = ld_frag(bp + (size_t)n * 512);
      acc[n] = __builtin_amdgcn_mfma_f32_16x16x32_bf16(a, b, acc[n], 0, 0, 0);
    }
  }

#pragma unroll
  for (int n = 0; n < 16; ++n) {
    int col = c0 + n * 16 + (lane & 15);
#pragma unroll
    for (int reg = 0; reg < 4; ++reg) {
      long row = bt0 + r0 + (lane >> 4) * 4 + reg;
      float v = acc[n][reg];
      if (MODE == 0) {
        int t = (int)(row & (NT - 1));
        long b = row >> 11;
        v += (t == 0) ? (bias_t0[col] + z0[b * NH + col]) : bias_t[col];
      } else {
        v += bout[col];
      }
      out[row * 512 + col] = v;
      if (MODE == 1 && ((row & (NT - 1)) == NT - 1)) last[(row >> 11) * 512 + col] = v;
    }
  }
}

// ---------------- sequential scan ----------------
// grid 4 x 512 threads; WG w owns batches [16w, 16w+16). No inter-WG sync.
// h state: LDS bf16 [2][16][512], XOR-swizzled. h also stored bf16 to the low
// half of buf's fp32 rows (P3 reads it from there).
__global__ __launch_bounds__(512, 2) void k_scan(float* __restrict__ buf,
                                                 const unsigned short* __restrict__ fragWc) {
  __shared__ __align__(16) unsigned short h_lds[2][16 * 512];  // 32KB
  unsigned short* hbuf = (unsigned short*)buf;
  const int tid = threadIdx.x;
  const int b0 = blockIdx.x * 16;
  const int wave = tid >> 6, lane = tid & 63;
  const int arow = lane & 15, bb = lane >> 4;
  const int c0 = wave * 64;
  const int swz = (arow & 7) << 3;

  // Wc fragments: kt=0,1 resident in VGPRs for the whole scan (issued first).
  const unsigned short* bW = fragWc + ((size_t)(wave * 4) * 64 + lane) * 8;
  bf16x8 br0[4], br1[4];
#pragma unroll
  for (int n = 0; n < 4; ++n) br0[n] = ld_frag(bW + (size_t)n * 512);
#pragma unroll
  for (int n = 0; n < 4; ++n) br1[n] = ld_frag(bW + (size_t)(32 + n) * 512);

  // ---- t = 0 : h0 = tanh(pre0). Read-all / barrier / write (bf16 writes alias
  // other threads' fp32 reads, so the phases must be separated).
  float v0[16];
#pragma unroll
  for (int i = 0; i < 16; ++i) v0[i] = buf[(size_t)(b0 + i) * TH + tid];
  __syncthreads();
#pragma unroll
  for (int i = 0; i < 16; ++i) {
    float h = fast_tanh(v0[i]);
    unsigned short hb = f2bf(h);
    hbuf[(size_t)(b0 + i) * (size_t)NT * 1024 + tid] = hb;
    h_lds[0][(i * 512 + tid) ^ ((i & 7) << 3)] = hb;
  }

  // per-lane global pointers at the t=1 row
  const float* pPre[4];
  unsigned short* pSt[4];
#pragma unroll
  for (int r = 0; r < 4; ++r) {
    int b = b0 + bb * 4 + r;
    pPre[r] = buf + (size_t)b * TH + 512 + c0 + arow;
    pSt[r]  = hbuf + (size_t)b * (size_t)NT * 1024 + 1024 + c0 + arow;
  }

  // preload pre(t=1)
  float pre[16];
#pragma unroll
  for (int n = 0; n < 4; ++n)
#pragma unroll
    for (int r = 0; r < 4; ++r) pre[n * 4 + r] = pPre[r][n * 16];

  __syncthreads();  // h_lds[0] visible to all waves

#define AIDX(k) ((arow * 512 + (k) * 32 + bb * 8) ^ swz)

#pragma unroll 1
  for (int t = 1; t < NT; ++t) {
    // issue streaming B prefetch (kt=2,3) first — independent of everything
    bf16x8 p0[4], p1[4];
#pragma unroll
    for (int n = 0; n < 4; ++n) p0[n] = ld_frag(bW + (size_t)(2 * 32 + n) * 512);
#pragma unroll
    for (int n = 0; n < 4; ++n) p1[n] = ld_frag(bW + (size_t)(3 * 32 + n) * 512);

    f32x4 acc[4];
#pragma unroll
    for (int n = 0; n < 4; ++n)
#pragma unroll
      for (int r = 0; r < 4; ++r) acc[n][r] = pre[n * 4 + r];

    const unsigned short* hs = h_lds[(t - 1) & 1];

    {
      bf16x8 a0 = ld_frag(hs + AIDX(0));
#pragma unroll
      for (int n = 0; n < 4; ++n)
        acc[n] = __builtin_amdgcn_mfma_f32_16x16x32_bf16(a0, br0[n], acc[n], 0, 0, 0);
      bf16x8 a1 = ld_frag(hs + AIDX(1));
#pragma unroll
      for (int n = 0; n < 4; ++n)
        acc[n] = __builtin_amdgcn_mfma_f32_16x16x32_bf16(a1, br1[n], acc[n], 0, 0, 0);
    }
#pragma unroll
    for (int kk = 2; kk < 16; kk += 2) {
      bf16x8 a0 = ld_frag(hs + AIDX(kk));
#pragma unroll
      for (int n = 0; n < 4; ++n)
        acc[n] = __builtin_amdgcn_mfma_f32_16x16x32_bf16(a0, p0[n], acc[n], 0, 0, 0);
      if (kk + 2 < 16) {
#pragma unroll
        for (int n = 0; n < 4; ++n) p0[n] = ld_frag(bW + (size_t)((kk + 2) * 32 + n) * 512);
      }
      bf16x8 a1 = ld_frag(hs + AIDX(kk + 1));
#pragma unroll
      for (int n = 0; n < 4; ++n)
        acc[n] = __builtin_amdgcn_mfma_f32_16x16x32_bf16(a1, p1[n], acc[n], 0, 0, 0);
      if (kk + 3 < 16) {
#pragma unroll
        for (int n = 0; n < 4; ++n) p1[n] = ld_frag(bW + (size_t)((kk + 3) * 32 + n) * 512);
      }
    }

    // prefetch pre(t+1) — issued while MFMAs drain; consumed next step
    if (t < NT - 1) {
#pragma unroll
      for (int r = 0; r < 4; ++r) pPre[r] += 512;
#pragma unroll
      for (int n = 0; n < 4; ++n)
#pragma unroll
        for (int r = 0; r < 4; ++r) pre[n * 4 + r] = pPre[r][n * 16];
    }

    unsigned short* hdst = h_lds[t & 1];
#pragma unroll
    for (int n = 0; n < 4; ++n)
#pragma unroll
      for (int r = 0; r < 4; ++r) {
        int b = bb * 4 + r;
        float h = fast_tanh(acc[n][r]);
        unsigned short hb = f2bf(h);
        pSt[r][n * 16] = hb;                                   // bf16 h -> global (P3 input)
        hdst[(b * 512 + c0 + n * 16 + arow) ^ ((b & 7) << 3)] = hb;
      }
#pragma unroll
    for (int r = 0; r < 4; ++r) pSt[r] += 1024;
    __syncthreads();
  }
#undef AIDX
}

// ---------------- launch ----------------
extern "C" void kernel_launch(void* const* d_in, const int* in_sizes, int n_in,
                              void* d_out, int out_size, void* d_ws, size_t ws_size,
                              hipStream_t stream) {
  const float* emb  = (const float*)d_in[0];
  const float* ll   = (const float*)d_in[1];
  const float* Whx  = (const float*)d_in[2];
  const float* bhx  = (const float*)d_in[3];
  const float* Wyh  = (const float*)d_in[4];
  const float* byh  = (const float*)d_in[5];
  const float* Wout = (const float*)d_in[6];
  const float* bout = (const float*)d_in[7];

  float* buf  = (float*)d_out;                       // [B*T, 512] pre -> h -> y (in place)
  float* last = buf + (size_t)NB * NT * NO;          // [B, O] tail

  char* ws = (char*)d_ws;                            // ~2.7 MB used
  unsigned short* fragWhx  = (unsigned short*)ws;                         // 512KB
  unsigned short* fragWc   = (unsigned short*)(ws + (512 * 512 * 2));     // 512KB
  unsigned short* fragWout = (unsigned short*)(ws + 2 * (512 * 512 * 2)); // 512KB
  float* z0      = (float*)(ws + 3 * (512 * 512 * 2));                    // 128KB
  float* bias_t0 = z0 + NB * NH;
  float* bias_t  = bias_t0 + NH;
  float* Wc_f32  = bias_t + NH;                                           // 1MB

  k_bias<<<1, 512, 0, stream>>>(Wyh, bout, bhx, byh, bias_t0, bias_t);
  k_z0<<<64, 512, 0, stream>>>(ll, Wyh, z0);
  k_wc<<<512, 512, 0, stream>>>(Wyh, Wout, Wc_f32);
  k_frag<<<128, 256, 0, stream>>>(Whx, fragWhx);     // Bm[d][j] = Whx[j][d]
  k_frag<<<128, 256, 0, stream>>>(Wc_f32, fragWc);   // Bm[k][j] = Wc[j][k]
  k_frag<<<128, 256, 0, stream>>>(Wout, fragWout);   // Bm[k][o] = Wout[o][k]

  // P1: pre = emb @ Whx^T + biases (t==0 rows get z0)
  k_gemm<0><<<2048, 512, 0, stream>>>(emb, fragWhx, buf, bias_t0, bias_t, z0, bout, last);
  // P2: sequential scan, h (bf16) in place over pre
  k_scan<<<4, 512, 0, stream>>>(buf, fragWc);
  // P3: y = h @ Wout^T + bout, in place over h; also fills `last`
  k_gemm<1><<<2048, 512, 0, stream>>>(buf, fragWout, buf, bias_t0, bias_t, z0, bout, last);
}

// Round 3
// 16133.575 us; speedup vs baseline: 1.2030x; 1.0928x over previous
//
#include <hip/hip_runtime.h>
#include <hip/hip_bf16.h>

// Jordan RNN restructured:
//   Wc = Wyh @ Wout  [H,H]
//   pre[b,t,:] = emb@Whx^T + bhx + byh + (t==0 ? last_logits@Wyh^T : Wyh@bout)
//   scan: h_t = tanh(pre_t + h_{t-1} @ Wc^T)     (per-batch independent!)
//   y_t  = h_t @ Wout^T + bout                    (time-parallel epilogue GEMM)
// Scan: 4 WGs (1/CU), 8 waves each. Wc kt=0..7 persistent in VGPRs (128/wave),
// kt=8..15 streamed from L2 with rotating prefetch. Raw s_barrier with
// lgkmcnt-only drain so global prefetch/stores stay in flight across steps.

#define NB 64
#define NT 2048
#define ND 512
#define NH 512
#define NO 512
#define TH (NT * NH)

typedef float f32x4 __attribute__((ext_vector_type(4)));
typedef __bf16 bf16x8 __attribute__((ext_vector_type(8)));
typedef unsigned short u16x8 __attribute__((ext_vector_type(8)));

__device__ __forceinline__ unsigned short f2bf(float x) {
  unsigned u = __builtin_bit_cast(unsigned, x);
  u += 0x7FFFu + ((u >> 16) & 1u);               // RNE
  return (unsigned short)(u >> 16);
}
__device__ __forceinline__ bf16x8 ld_frag(const unsigned short* p) {
  u16x8 r = *(const u16x8*)p;
  return __builtin_bit_cast(bf16x8, r);
}
// tanh via hardware exp2/rcp: abs err ~1e-6, inf-safe.
__device__ __forceinline__ float fast_tanh(float x) {
  float ax = __builtin_fabsf(x);
  float e = __builtin_amdgcn_exp2f(ax * 2.8853900817779268f);  // e^(2|x|)
  float r = 1.0f - 2.0f * __builtin_amdgcn_rcpf(e + 1.0f);
  return __builtin_copysignf(r, x);
}

// ---------------- prep kernels ----------------

__global__ void k_bias(const float* __restrict__ Wyh, const float* __restrict__ bout,
                       const float* __restrict__ bhx, const float* __restrict__ byh,
                       float* bias_t0, float* bias_t) {
  int j = threadIdx.x;
  const float* row = Wyh + j * NO;
  float acc = 0.f;
  for (int o = 0; o < NO; ++o) acc += row[o] * bout[o];
  bias_t0[j] = bhx[j] + byh[j];
  bias_t[j]  = bhx[j] + byh[j] + acc;
}

__global__ void k_z0(const float* __restrict__ ll, const float* __restrict__ Wyh,
                     float* z0) {
  int b = blockIdx.x, j = threadIdx.x;
  const float* row = Wyh + j * NO;
  const float* lr = ll + b * NO;
  float acc = 0.f;
  for (int o = 0; o < NO; ++o) acc += lr[o] * row[o];
  z0[b * NH + j] = acc;
}

__global__ void k_wc(const float* __restrict__ Wyh, const float* __restrict__ Wout,
                     float* Wc) {
  int j = blockIdx.x, k = threadIdx.x;
  float acc = 0.f;
  for (int o = 0; o < NO; ++o) acc += Wyh[j * NO + o] * Wout[o * NH + k];
  Wc[j * NH + k] = acc;
}

// Build MFMA B-operand fragments for Bm = src^T (src is [N=512 rows][K=512 cols]).
// Fragment for 16x16x32: lane l holds B[kt*32 + (l>>4)*8 + i][nt*16 + (l&15)], i=0..7.
__global__ void k_frag(const float* __restrict__ src, unsigned short* __restrict__ dst) {
  int gid = blockIdx.x * 256 + threadIdx.x;  // 32768 total
  int lane = gid & 63, tidx = gid >> 6;
  int nt = tidx & 31, kt = tidx >> 5;
  const float* s = src + (size_t)(nt * 16 + (lane & 15)) * 512 + kt * 32 + (lane >> 4) * 8;
  unsigned short* d = dst + (size_t)gid * 8;
#pragma unroll
  for (int i = 0; i < 8; ++i) d[i] = f2bf(s[i]);
}

// ---------------- big GEMM (P1 and P3) ----------------
// MODE 0 (P1): A fp32 (emb); bias = (t==0 ? bias_t0+z0 : bias_t)
// MODE 1 (P3): A bf16 packed in low half of each fp32 row (h from scan);
//              bias = bout; in-place (A aliases out); t==T-1 rows -> last[]
template <int MODE>
__global__ __launch_bounds__(512) void k_gemm(
    const void* __restrict__ Ain, const unsigned short* __restrict__ fragB,
    float* __restrict__ out, const float* __restrict__ bias_t0,
    const float* __restrict__ bias_t, const float* __restrict__ z0,
    const float* __restrict__ bout, float* __restrict__ last) {
  __shared__ __align__(16) unsigned short a_lds[64 * 512];  // 64KB, XOR-swizzled bf16
  int tid = threadIdx.x;
  long bt0 = (long)blockIdx.x * 64;

  if (MODE == 0) {
    const float* A = (const float*)Ain;
#pragma unroll
    for (int it = 0; it < 16; ++it) {
      int chunk = it * 512 + tid;
      int r = chunk >> 7, c4 = chunk & 127;
      float4 v = ((const float4*)A)[(bt0 + r) * 128 + c4];
      int idx = (r * 512 + c4 * 4) ^ ((r & 7) << 3);
      unsigned short* p = &a_lds[idx];
      p[0] = f2bf(v.x); p[1] = f2bf(v.y); p[2] = f2bf(v.z); p[3] = f2bf(v.w);
    }
  } else {
    const unsigned short* A = (const unsigned short*)Ain;
#pragma unroll
    for (int it = 0; it < 8; ++it) {
      int chunk = it * 512 + tid;           // 4096 chunks of 8 u16
      int r = chunk >> 6, c8 = chunk & 63;
      u16x8 v = *(const u16x8*)(A + (size_t)(bt0 + r) * 1024 + c8 * 8);
      int idx = (r * 512 + c8 * 8) ^ ((r & 7) << 3);
      *(u16x8*)&a_lds[idx] = v;
    }
  }
  __syncthreads();

  int wave = tid >> 6, lane = tid & 63;
  int r0 = (wave & 3) * 16, c0 = (wave >> 2) * 256;
  f32x4 acc[16];
#pragma unroll
  for (int n = 0; n < 16; ++n) acc[n] = (f32x4){0.f, 0.f, 0.f, 0.f};
  int arow = r0 + (lane & 15);

  for (int kt = 0; kt < 16; ++kt) {
    int aidx = (arow * 512 + kt * 32 + (lane >> 4) * 8) ^ ((arow & 7) << 3);
    bf16x8 a = ld_frag(&a_lds[aidx]);
    const unsigned short* bp = fragB + ((size_t)(kt * 32 + (c0 >> 4)) * 64 + lane) * 8;
#pragma unroll
    for (int n = 0; n < 16; ++n) {
      bf16x8 b = ld_frag(bp + (size_t)n * 512);
      acc[n] = __builtin_amdgcn_mfma_f32_16x16x32_bf16(a, b, acc[n], 0, 0, 0);
    }
  }

#pragma unroll
  for (int n = 0; n < 16; ++n) {
    int col = c0 + n * 16 + (lane & 15);
#pragma unroll
    for (int reg = 0; reg < 4; ++reg) {
      long row = bt0 + r0 + (lane >> 4) * 4 + reg;
      float v = acc[n][reg];
      if (MODE == 0) {
        int t = (int)(row & (NT - 1));
        long b = row >> 11;
        v += (t == 0) ? (bias_t0[col] + z0[b * NH + col]) : bias_t[col];
      } else {
        v += bout[col];
      }
      out[row * 512 + col] = v;
      if (MODE == 1 && ((row & (NT - 1)) == NT - 1)) last[(row >> 11) * 512 + col] = v;
    }
  }
}

// ---------------- sequential scan ----------------
// grid 4 x 512 threads; WG w owns batches [16w, 16w+16). No inter-WG sync.
// h state: LDS bf16 [2][16][512], XOR-swizzled. h also stored bf16 to the low
// half of buf's fp32 rows (P3 reads it from there).
__global__ __launch_bounds__(512, 2) void k_scan(float* __restrict__ buf,
                                                 const unsigned short* __restrict__ fragWc) {
  __shared__ __align__(16) unsigned short h_lds[2][16 * 512];  // 32KB
  unsigned short* hbuf = (unsigned short*)buf;
  const int tid = threadIdx.x;
  const int b0 = blockIdx.x * 16;
  const int wave = tid >> 6, lane = tid & 63;
  const int arow = lane & 15, bb = lane >> 4;
  const int c0 = wave * 64;
  const int swz = (arow & 7) << 3;

  // Wc fragments kt=0..7 resident in VGPRs for the whole scan (128 VGPR).
  const unsigned short* bW = fragWc + ((size_t)(wave * 4) * 64 + lane) * 8;
  bf16x8 br[8][4];
#pragma unroll
  for (int kt = 0; kt < 8; ++kt)
#pragma unroll
    for (int n = 0; n < 4; ++n) br[kt][n] = ld_frag(bW + (size_t)(kt * 32 + n) * 512);

  // ---- t = 0 : h0 = tanh(pre0). Read-all / barrier / write (bf16 writes alias
  // other threads' fp32 reads, so the phases must be separated).
  float v0[16];
#pragma unroll
  for (int i = 0; i < 16; ++i) v0[i] = buf[(size_t)(b0 + i) * TH + tid];
  __syncthreads();
#pragma unroll
  for (int i = 0; i < 16; ++i) {
    float h = fast_tanh(v0[i]);
    unsigned short hb = f2bf(h);
    hbuf[(size_t)(b0 + i) * (size_t)NT * 1024 + tid] = hb;
    h_lds[0][(i * 512 + tid) ^ ((i & 7) << 3)] = hb;
  }

  // per-lane global pointers at the t=1 row
  const float* pPre[4];
  unsigned short* pSt[4];
#pragma unroll
  for (int r = 0; r < 4; ++r) {
    int b = b0 + bb * 4 + r;
    pPre[r] = buf + (size_t)b * TH + 512 + c0 + arow;
    pSt[r]  = hbuf + (size_t)b * (size_t)NT * 1024 + 1024 + c0 + arow;
  }

  // preload pre(t=1)
  float pre[16];
#pragma unroll
  for (int n = 0; n < 4; ++n)
#pragma unroll
    for (int r = 0; r < 4; ++r) pre[n * 4 + r] = pPre[r][n * 16];

  __syncthreads();  // h_lds[0] visible to all waves

#define AIDX(k) ((arow * 512 + (k) * 32 + bb * 8) ^ swz)

#pragma unroll 1
  for (int t = 1; t < NT; ++t) {
    // consume pre into acc, then immediately re-issue pre(t+1) loads: they get
    // the whole MFMA phase + barrier to land (raw barrier won't drain them).
    f32x4 acc[4];
#pragma unroll
    for (int n = 0; n < 4; ++n)
#pragma unroll
      for (int r = 0; r < 4; ++r) acc[n][r] = pre[n * 4 + r];

    if (t < NT - 1) {
#pragma unroll
      for (int r = 0; r < 4; ++r) pPre[r] += 512;
#pragma unroll
      for (int n = 0; n < 4; ++n)
#pragma unroll
        for (int r = 0; r < 4; ++r) pre[n * 4 + r] = pPre[r][n * 16];
    }

    // issue streaming-B prefetch for kt=8,9 (consumed after the persistent half)
    bf16x8 p0[4], p1[4];
#pragma unroll
    for (int n = 0; n < 4; ++n) p0[n] = ld_frag(bW + (size_t)(8 * 32 + n) * 512);
#pragma unroll
    for (int n = 0; n < 4; ++n) p1[n] = ld_frag(bW + (size_t)(9 * 32 + n) * 512);

    const unsigned short* hs = h_lds[(t - 1) & 1];

    // persistent half: kt = 0..7, B already in registers
#pragma unroll
    for (int kt = 0; kt < 8; ++kt) {
      bf16x8 a = ld_frag(hs + AIDX(kt));
#pragma unroll
      for (int n = 0; n < 4; ++n)
        acc[n] = __builtin_amdgcn_mfma_f32_16x16x32_bf16(a, br[kt][n], acc[n], 0, 0, 0);
    }

    // streamed half: kt = 8..15, rotating 2-group prefetch
#pragma unroll
    for (int kk = 8; kk < 16; kk += 2) {
      bf16x8 a0 = ld_frag(hs + AIDX(kk));
#pragma unroll
      for (int n = 0; n < 4; ++n)
        acc[n] = __builtin_amdgcn_mfma_f32_16x16x32_bf16(a0, p0[n], acc[n], 0, 0, 0);
      if (kk + 2 < 16) {
#pragma unroll
        for (int n = 0; n < 4; ++n) p0[n] = ld_frag(bW + (size_t)((kk + 2) * 32 + n) * 512);
      }
      bf16x8 a1 = ld_frag(hs + AIDX(kk + 1));
#pragma unroll
      for (int n = 0; n < 4; ++n)
        acc[n] = __builtin_amdgcn_mfma_f32_16x16x32_bf16(a1, p1[n], acc[n], 0, 0, 0);
      if (kk + 3 < 16) {
#pragma unroll
        for (int n = 0; n < 4; ++n) p1[n] = ld_frag(bW + (size_t)((kk + 3) * 32 + n) * 512);
      }
    }

    // epilogue: tanh -> bf16 h -> global (P3 input) + LDS (next step's A)
    unsigned short* hdst = h_lds[t & 1];
#pragma unroll
    for (int n = 0; n < 4; ++n)
#pragma unroll
      for (int r = 0; r < 4; ++r) {
        int b = bb * 4 + r;
        float h = fast_tanh(acc[n][r]);
        unsigned short hb = f2bf(h);
        pSt[r][n * 16] = hb;
        hdst[(b * 512 + c0 + n * 16 + arow) ^ ((b & 7) << 3)] = hb;
      }
#pragma unroll
    for (int r = 0; r < 4; ++r) pSt[r] += 1024;

    // lgkm-only drain + raw barrier: LDS h-exchange synced, global loads/stores
    // stay in flight across the step boundary (no vmcnt(0) drain).
    asm volatile("s_waitcnt lgkmcnt(0)" ::: "memory");
    __builtin_amdgcn_s_barrier();
    asm volatile("" ::: "memory");
  }
#undef AIDX
}

// ---------------- launch ----------------
extern "C" void kernel_launch(void* const* d_in, const int* in_sizes, int n_in,
                              void* d_out, int out_size, void* d_ws, size_t ws_size,
                              hipStream_t stream) {
  const float* emb  = (const float*)d_in[0];
  const float* ll   = (const float*)d_in[1];
  const float* Whx  = (const float*)d_in[2];
  const float* bhx  = (const float*)d_in[3];
  const float* Wyh  = (const float*)d_in[4];
  const float* byh  = (const float*)d_in[5];
  const float* Wout = (const float*)d_in[6];
  const float* bout = (const float*)d_in[7];

  float* buf  = (float*)d_out;                       // [B*T, 512] pre -> h -> y (in place)
  float* last = buf + (size_t)NB * NT * NO;          // [B, O] tail

  char* ws = (char*)d_ws;                            // ~2.7 MB used
  unsigned short* fragWhx  = (unsigned short*)ws;                         // 512KB
  unsigned short* fragWc   = (unsigned short*)(ws + (512 * 512 * 2));     // 512KB
  unsigned short* fragWout = (unsigned short*)(ws + 2 * (512 * 512 * 2)); // 512KB
  float* z0      = (float*)(ws + 3 * (512 * 512 * 2));                    // 128KB
  float* bias_t0 = z0 + NB * NH;
  float* bias_t  = bias_t0 + NH;
  float* Wc_f32  = bias_t + NH;                                           // 1MB

  k_bias<<<1, 512, 0, stream>>>(Wyh, bout, bhx, byh, bias_t0, bias_t);
  k_z0<<<64, 512, 0, stream>>>(ll, Wyh, z0);
  k_wc<<<512, 512, 0, stream>>>(Wyh, Wout, Wc_f32);
  k_frag<<<128, 256, 0, stream>>>(Whx, fragWhx);     // Bm[d][j] = Whx[j][d]
  k_frag<<<128, 256, 0, stream>>>(Wc_f32, fragWc);   // Bm[k][j] = Wc[j][k]
  k_frag<<<128, 256, 0, stream>>>(Wout, fragWout);   // Bm[k][o] = Wout[o][k]

  // P1: pre = emb @ Whx^T + biases (t==0 rows get z0)
  k_gemm<0><<<2048, 512, 0, stream>>>(emb, fragWhx, buf, bias_t0, bias_t, z0, bout, last);
  // P2: sequential scan, h (bf16) in place over pre
  k_scan<<<4, 512, 0, stream>>>(buf, fragWc);
  // P3: y = h @ Wout^T + bout, in place over h; also fills `last`
  k_gemm<1><<<2048, 512, 0, stream>>>(buf, fragWout, buf, bias_t0, bias_t, z0, bout, last);
}

// Round 4
// 14778.773 us; speedup vs baseline: 1.3133x; 1.0917x over previous
//
#include <hip/hip_runtime.h>
#include <hip/hip_bf16.h>

// Jordan RNN restructured:
//   Wc = Wyh @ Wout  [H,H]
//   pre[b,t,:] = emb@Whx^T + bhx + byh + (t==0 ? last_logits@Wyh^T : Wyh@bout)
//   scan: h_t = tanh(pre_t + h_{t-1} @ Wc^T)     (per-batch independent!)
//   y_t  = h_t @ Wout^T + bout                    (time-parallel epilogue GEMM)
// Scan: 4 WGs (1/CU), 8 waves each. Wc kt=0..7 pinned in VGPRs via opaque asm
// (128 VGPR/wave), kt=8..15 streamed from L2 with rotating prefetch. Raw
// s_barrier with lgkmcnt-only drain so global traffic spans step boundaries.

#define NB 64
#define NT 2048
#define ND 512
#define NH 512
#define NO 512
#define TH (NT * NH)

typedef float f32x4 __attribute__((ext_vector_type(4)));
typedef __bf16 bf16x8 __attribute__((ext_vector_type(8)));
typedef unsigned short u16x8 __attribute__((ext_vector_type(8)));

__device__ __forceinline__ unsigned short f2bf(float x) {
  unsigned u = __builtin_bit_cast(unsigned, x);
  u += 0x7FFFu + ((u >> 16) & 1u);               // RNE
  return (unsigned short)(u >> 16);
}
__device__ __forceinline__ bf16x8 ld_frag(const unsigned short* p) {
  u16x8 r = *(const u16x8*)p;
  return __builtin_bit_cast(bf16x8, r);
}
__device__ __forceinline__ f32x4 ld_frag4(const unsigned short* p) {
  return *(const f32x4*)p;
}
// tanh via hardware exp2/rcp: abs err ~1e-6, inf-safe.
__device__ __forceinline__ float fast_tanh(float x) {
  float ax = __builtin_fabsf(x);
  float e = __builtin_amdgcn_exp2f(ax * 2.8853900817779268f);  // e^(2|x|)
  float r = 1.0f - 2.0f * __builtin_amdgcn_rcpf(e + 1.0f);
  return __builtin_copysignf(r, x);
}

// ---------------- prep kernels ----------------

__global__ void k_bias(const float* __restrict__ Wyh, const float* __restrict__ bout,
                       const float* __restrict__ bhx, const float* __restrict__ byh,
                       float* bias_t0, float* bias_t) {
  int j = threadIdx.x;
  const float* row = Wyh + j * NO;
  float acc = 0.f;
  for (int o = 0; o < NO; ++o) acc += row[o] * bout[o];
  bias_t0[j] = bhx[j] + byh[j];
  bias_t[j]  = bhx[j] + byh[j] + acc;
}

__global__ void k_z0(const float* __restrict__ ll, const float* __restrict__ Wyh,
                     float* z0) {
  int b = blockIdx.x, j = threadIdx.x;
  const float* row = Wyh + j * NO;
  const float* lr = ll + b * NO;
  float acc = 0.f;
  for (int o = 0; o < NO; ++o) acc += lr[o] * row[o];
  z0[b * NH + j] = acc;
}

__global__ void k_wc(const float* __restrict__ Wyh, const float* __restrict__ Wout,
                     float* Wc) {
  int j = blockIdx.x, k = threadIdx.x;
  float acc = 0.f;
  for (int o = 0; o < NO; ++o) acc += Wyh[j * NO + o] * Wout[o * NH + k];
  Wc[j * NH + k] = acc;
}

// Build MFMA B-operand fragments for Bm = src^T (src is [N=512 rows][K=512 cols]).
// Fragment for 16x16x32: lane l holds B[kt*32 + (l>>4)*8 + i][nt*16 + (l&15)], i=0..7.
__global__ void k_frag(const float* __restrict__ src, unsigned short* __restrict__ dst) {
  int gid = blockIdx.x * 256 + threadIdx.x;  // 32768 total
  int lane = gid & 63, tidx = gid >> 6;
  int nt = tidx & 31, kt = tidx >> 5;
  const float* s = src + (size_t)(nt * 16 + (lane & 15)) * 512 + kt * 32 + (lane >> 4) * 8;
  unsigned short* d = dst + (size_t)gid * 8;
#pragma unroll
  for (int i = 0; i < 8; ++i) d[i] = f2bf(s[i]);
}

// ---------------- big GEMM (P1 and P3) ----------------
// MODE 0 (P1): A fp32 (emb); bias = (t==0 ? bias_t0+z0 : bias_t)
// MODE 1 (P3): A bf16 packed in low half of each fp32 row (h from scan);
//              bias = bout; in-place (A aliases out); t==T-1 rows -> last[]
template <int MODE>
__global__ __launch_bounds__(512) void k_gemm(
    const void* __restrict__ Ain, const unsigned short* __restrict__ fragB,
    float* __restrict__ out, const float* __restrict__ bias_t0,
    const float* __restrict__ bias_t, const float* __restrict__ z0,
    const float* __restrict__ bout, float* __restrict__ last) {
  __shared__ __align__(16) unsigned short a_lds[64 * 512];  // 64KB, XOR-swizzled bf16
  int tid = threadIdx.x;
  long bt0 = (long)blockIdx.x * 64;

  if (MODE == 0) {
    const float* A = (const float*)Ain;
#pragma unroll
    for (int it = 0; it < 16; ++it) {
      int chunk = it * 512 + tid;
      int r = chunk >> 7, c4 = chunk & 127;
      float4 v = ((const float4*)A)[(bt0 + r) * 128 + c4];
      int idx = (r * 512 + c4 * 4) ^ ((r & 7) << 3);
      unsigned short* p = &a_lds[idx];
      p[0] = f2bf(v.x); p[1] = f2bf(v.y); p[2] = f2bf(v.z); p[3] = f2bf(v.w);
    }
  } else {
    const unsigned short* A = (const unsigned short*)Ain;
#pragma unroll
    for (int it = 0; it < 8; ++it) {
      int chunk = it * 512 + tid;           // 4096 chunks of 8 u16
      int r = chunk >> 6, c8 = chunk & 63;
      u16x8 v = *(const u16x8*)(A + (size_t)(bt0 + r) * 1024 + c8 * 8);
      int idx = (r * 512 + c8 * 8) ^ ((r & 7) << 3);
      *(u16x8*)&a_lds[idx] = v;
    }
  }
  __syncthreads();

  int wave = tid >> 6, lane = tid & 63;
  int r0 = (wave & 3) * 16, c0 = (wave >> 2) * 256;
  f32x4 acc[16];
#pragma unroll
  for (int n = 0; n < 16; ++n) acc[n] = (f32x4){0.f, 0.f, 0.f, 0.f};
  int arow = r0 + (lane & 15);

  for (int kt = 0; kt < 16; ++kt) {
    int aidx = (arow * 512 + kt * 32 + (lane >> 4) * 8) ^ ((arow & 7) << 3);
    bf16x8 a = ld_frag(&a_lds[aidx]);
    const unsigned short* bp = fragB + ((size_t)(kt * 32 + (c0 >> 4)) * 64 + lane) * 8;
#pragma unroll
    for (int n = 0; n < 16; ++n) {
      bf16x8 b = ld_frag(bp + (size_t)n * 512);
      acc[n] = __builtin_amdgcn_mfma_f32_16x16x32_bf16(a, b, acc[n], 0, 0, 0);
    }
  }

#pragma unroll
  for (int n = 0; n < 16; ++n) {
    int col = c0 + n * 16 + (lane & 15);
#pragma unroll
    for (int reg = 0; reg < 4; ++reg) {
      long row = bt0 + r0 + (lane >> 4) * 4 + reg;
      float v = acc[n][reg];
      if (MODE == 0) {
        int t = (int)(row & (NT - 1));
        long b = row >> 11;
        v += (t == 0) ? (bias_t0[col] + z0[b * NH + col]) : bias_t[col];
      } else {
        v += bout[col];
      }
      out[row * 512 + col] = v;
      if (MODE == 1 && ((row & (NT - 1)) == NT - 1)) last[(row >> 11) * 512 + col] = v;
    }
  }
}

// ---------------- sequential scan ----------------
// grid 4 x 512 threads; WG w owns batches [16w, 16w+16). No inter-WG sync.
// h state: LDS bf16 [2][16][512], XOR-swizzled. h also stored bf16 to the low
// half of buf's fp32 rows (P3 reads it from there).
__global__ __launch_bounds__(512, 2) void k_scan(float* __restrict__ buf,
                                                 const unsigned short* __restrict__ fragWc) {
  __shared__ __align__(16) unsigned short h_lds[2][16 * 512];  // 32KB
  unsigned short* hbuf = (unsigned short*)buf;
  const int tid = threadIdx.x;
  const int b0 = blockIdx.x * 16;
  const int wave = tid >> 6, lane = tid & 63;
  const int arow = lane & 15, bb = lane >> 4;
  const int c0 = wave * 64;
  const int swz = (arow & 7) << 3;

  // Wc fragments kt=0..7: load once, PIN in VGPRs via opaque asm (the compiler
  // otherwise rematerializes these loop-invariant loads each step — R3's bug:
  // VGPR_Count stayed 128 and the full 512KB streamed from L2 every step).
  const unsigned short* bW = fragWc + ((size_t)(wave * 4) * 64 + lane) * 8;
  f32x4 br[8][4];
#pragma unroll
  for (int kt = 0; kt < 8; ++kt)
#pragma unroll
    for (int n = 0; n < 4; ++n) br[kt][n] = ld_frag4(bW + (size_t)(kt * 32 + n) * 512);
#pragma unroll
  for (int kt = 0; kt < 8; ++kt)
#pragma unroll
    for (int n = 0; n < 4; ++n) asm volatile("" : "+v"(br[kt][n]));

  // ---- t = 0 : h0 = tanh(pre0). Read-all / barrier / write (bf16 writes alias
  // other threads' fp32 reads, so the phases must be separated).
  float v0[16];
#pragma unroll
  for (int i = 0; i < 16; ++i) v0[i] = buf[(size_t)(b0 + i) * TH + tid];
  __syncthreads();
#pragma unroll
  for (int i = 0; i < 16; ++i) {
    float h = fast_tanh(v0[i]);
    unsigned short hb = f2bf(h);
    hbuf[(size_t)(b0 + i) * (size_t)NT * 1024 + tid] = hb;
    h_lds[0][(i * 512 + tid) ^ ((i & 7) << 3)] = hb;
  }

  // per-lane global pointers at the t=1 row
  const float* pPre[4];
  unsigned short* pSt[4];
#pragma unroll
  for (int r = 0; r < 4; ++r) {
    int b = b0 + bb * 4 + r;
    pPre[r] = buf + (size_t)b * TH + 512 + c0 + arow;
    pSt[r]  = hbuf + (size_t)b * (size_t)NT * 1024 + 1024 + c0 + arow;
  }

  // preload pre(t=1)
  float pre[16];
#pragma unroll
  for (int n = 0; n < 4; ++n)
#pragma unroll
    for (int r = 0; r < 4; ++r) pre[n * 4 + r] = pPre[r][n * 16];

  __syncthreads();  // h_lds[0] visible to all waves

#define AIDX(k) ((arow * 512 + (k) * 32 + bb * 8) ^ swz)

#pragma unroll 1
  for (int t = 1; t < NT; ++t) {
    // 1) issue streaming-B prefetch for kt=8,9 first (consumed mid-step)
    bf16x8 p0[4], p1[4];
#pragma unroll
    for (int n = 0; n < 4; ++n) p0[n] = ld_frag(bW + (size_t)(8 * 32 + n) * 512);
#pragma unroll
    for (int n = 0; n < 4; ++n) p1[n] = ld_frag(bW + (size_t)(9 * 32 + n) * 512);

    // 2) consume pre into acc, then immediately issue pre(t+1) loads (consumed
    //    next step; raw barrier won't drain them)
    f32x4 acc[4];
#pragma unroll
    for (int n = 0; n < 4; ++n)
#pragma unroll
      for (int r = 0; r < 4; ++r) acc[n][r] = pre[n * 4 + r];

    if (t < NT - 1) {
#pragma unroll
      for (int r = 0; r < 4; ++r) pPre[r] += 512;
#pragma unroll
      for (int n = 0; n < 4; ++n)
#pragma unroll
        for (int r = 0; r < 4; ++r) pre[n * 4 + r] = pPre[r][n * 16];
    }

    const unsigned short* hs = h_lds[(t - 1) & 1];

    // persistent half: kt = 0..7, B resident in registers
#pragma unroll
    for (int kt = 0; kt < 8; ++kt) {
      bf16x8 a = ld_frag(hs + AIDX(kt));
#pragma unroll
      for (int n = 0; n < 4; ++n)
        acc[n] = __builtin_amdgcn_mfma_f32_16x16x32_bf16(
            a, __builtin_bit_cast(bf16x8, br[kt][n]), acc[n], 0, 0, 0);
    }

    // streamed half: kt = 8..15, rotating 2-group prefetch
#pragma unroll
    for (int kk = 8; kk < 16; kk += 2) {
      bf16x8 a0 = ld_frag(hs + AIDX(kk));
#pragma unroll
      for (int n = 0; n < 4; ++n)
        acc[n] = __builtin_amdgcn_mfma_f32_16x16x32_bf16(a0, p0[n], acc[n], 0, 0, 0);
      if (kk + 2 < 16) {
#pragma unroll
        for (int n = 0; n < 4; ++n) p0[n] = ld_frag(bW + (size_t)((kk + 2) * 32 + n) * 512);
      }
      bf16x8 a1 = ld_frag(hs + AIDX(kk + 1));
#pragma unroll
      for (int n = 0; n < 4; ++n)
        acc[n] = __builtin_amdgcn_mfma_f32_16x16x32_bf16(a1, p1[n], acc[n], 0, 0, 0);
      if (kk + 3 < 16) {
#pragma unroll
        for (int n = 0; n < 4; ++n) p1[n] = ld_frag(bW + (size_t)((kk + 3) * 32 + n) * 512);
      }
    }

    // epilogue: tanh -> bf16 h -> global (P3 input) + LDS (next step's A)
    unsigned short* hdst = h_lds[t & 1];
#pragma unroll
    for (int n = 0; n < 4; ++n)
#pragma unroll
      for (int r = 0; r < 4; ++r) {
        int b = bb * 4 + r;
        float h = fast_tanh(acc[n][r]);
        unsigned short hb = f2bf(h);
        pSt[r][n * 16] = hb;
        hdst[(b * 512 + c0 + n * 16 + arow) ^ ((b & 7) << 3)] = hb;
      }
#pragma unroll
    for (int r = 0; r < 4; ++r) pSt[r] += 1024;

    // lgkm-only drain + raw barrier: LDS h-exchange synced, global loads/stores
    // stay in flight across the step boundary (no vmcnt(0) drain).
    asm volatile("s_waitcnt lgkmcnt(0)" ::: "memory");
    __builtin_amdgcn_s_barrier();
    asm volatile("" ::: "memory");
  }
#undef AIDX
}

// ---------------- launch ----------------
extern "C" void kernel_launch(void* const* d_in, const int* in_sizes, int n_in,
                              void* d_out, int out_size, void* d_ws, size_t ws_size,
                              hipStream_t stream) {
  const float* emb  = (const float*)d_in[0];
  const float* ll   = (const float*)d_in[1];
  const float* Whx  = (const float*)d_in[2];
  const float* bhx  = (const float*)d_in[3];
  const float* Wyh  = (const float*)d_in[4];
  const float* byh  = (const float*)d_in[5];
  const float* Wout = (const float*)d_in[6];
  const float* bout = (const float*)d_in[7];

  float* buf  = (float*)d_out;                       // [B*T, 512] pre -> h -> y (in place)
  float* last = buf + (size_t)NB * NT * NO;          // [B, O] tail

  char* ws = (char*)d_ws;                            // ~2.7 MB used
  unsigned short* fragWhx  = (unsigned short*)ws;                         // 512KB
  unsigned short* fragWc   = (unsigned short*)(ws + (512 * 512 * 2));     // 512KB
  unsigned short* fragWout = (unsigned short*)(ws + 2 * (512 * 512 * 2)); // 512KB
  float* z0      = (float*)(ws + 3 * (512 * 512 * 2));                    // 128KB
  float* bias_t0 = z0 + NB * NH;
  float* bias_t  = bias_t0 + NH;
  float* Wc_f32  = bias_t + NH;                                           // 1MB

  k_bias<<<1, 512, 0, stream>>>(Wyh, bout, bhx, byh, bias_t0, bias_t);
  k_z0<<<64, 512, 0, stream>>>(ll, Wyh, z0);
  k_wc<<<512, 512, 0, stream>>>(Wyh, Wout, Wc_f32);
  k_frag<<<128, 256, 0, stream>>>(Whx, fragWhx);     // Bm[d][j] = Whx[j][d]
  k_frag<<<128, 256, 0, stream>>>(Wc_f32, fragWc);   // Bm[k][j] = Wc[j][k]
  k_frag<<<128, 256, 0, stream>>>(Wout, fragWout);   // Bm[k][o] = Wout[o][k]

  // P1: pre = emb @ Whx^T + biases (t==0 rows get z0)
  k_gemm<0><<<2048, 512, 0, stream>>>(emb, fragWhx, buf, bias_t0, bias_t, z0, bout, last);
  // P2: sequential scan, h (bf16) in place over pre
  k_scan<<<4, 512, 0, stream>>>(buf, fragWc);
  // P3: y = h @ Wout^T + bout, in place over h; also fills `last`
  k_gemm<1><<<2048, 512, 0, stream>>>(buf, fragWout, buf, bias_t0, bias_t, z0, bout, last);
}

// Round 5
// 14756.764 us; speedup vs baseline: 1.3153x; 1.0015x over previous
//
#include <hip/hip_runtime.h>
#include <hip/hip_bf16.h>

// Jordan RNN restructured:
//   Wc = Wyh @ Wout  [H,H]
//   pre[b,t,:] = emb@Whx^T + bhx + byh + (t==0 ? last_logits@Wyh^T : Wyh@bout)
//   scan: h_t = tanh(pre_t + h_{t-1} @ Wc^T)     (per-batch independent!)
//   y_t  = h_t @ Wout^T + bout                    (time-parallel epilogue GEMM)
// Scan: 4 WGs (1/CU), 8 waves each. Wc kt=0..7 pinned in VGPRs via opaque asm
// (128 VGPR/wave), kt=8..15 streamed from L2 with rotating prefetch. Raw
// s_barrier with lgkmcnt-only drain so global traffic spans step boundaries.

#define NB 64
#define NT 2048
#define ND 512
#define NH 512
#define NO 512
#define TH (NT * NH)

typedef float f32x4 __attribute__((ext_vector_type(4)));
typedef __bf16 bf16x8 __attribute__((ext_vector_type(8)));
typedef unsigned short u16x8 __attribute__((ext_vector_type(8)));

__device__ __forceinline__ unsigned short f2bf(float x) {
  unsigned u = __builtin_bit_cast(unsigned, x);
  u += 0x7FFFu + ((u >> 16) & 1u);               // RNE
  return (unsigned short)(u >> 16);
}
__device__ __forceinline__ bf16x8 ld_frag(const unsigned short* p) {
  u16x8 r = *(const u16x8*)p;
  return __builtin_bit_cast(bf16x8, r);
}
__device__ __forceinline__ f32x4 ld_frag4(const unsigned short* p) {
  return *(const f32x4*)p;
}
// tanh via hardware exp2/rcp: abs err ~1e-6, inf-safe.
__device__ __forceinline__ float fast_tanh(float x) {
  float ax = __builtin_fabsf(x);
  float e = __builtin_amdgcn_exp2f(ax * 2.8853900817779268f);  // e^(2|x|)
  float r = 1.0f - 2.0f * __builtin_amdgcn_rcpf(e + 1.0f);
  return __builtin_copysignf(r, x);
}

// ---------------- prep kernels ----------------

__global__ void k_bias(const float* __restrict__ Wyh, const float* __restrict__ bout,
                       const float* __restrict__ bhx, const float* __restrict__ byh,
                       float* bias_t0, float* bias_t) {
  int j = threadIdx.x;
  const float* row = Wyh + j * NO;
  float acc = 0.f;
  for (int o = 0; o < NO; ++o) acc += row[o] * bout[o];
  bias_t0[j] = bhx[j] + byh[j];
  bias_t[j]  = bhx[j] + byh[j] + acc;
}

__global__ void k_z0(const float* __restrict__ ll, const float* __restrict__ Wyh,
                     float* z0) {
  int b = blockIdx.x, j = threadIdx.x;
  const float* row = Wyh + j * NO;
  const float* lr = ll + b * NO;
  float acc = 0.f;
  for (int o = 0; o < NO; ++o) acc += lr[o] * row[o];
  z0[b * NH + j] = acc;
}

__global__ void k_wc(const float* __restrict__ Wyh, const float* __restrict__ Wout,
                     float* Wc) {
  int j = blockIdx.x, k = threadIdx.x;
  float acc = 0.f;
  for (int o = 0; o < NO; ++o) acc += Wyh[j * NO + o] * Wout[o * NH + k];
  Wc[j * NH + k] = acc;
}

// Build MFMA B-operand fragments for Bm = src^T (src is [N=512 rows][K=512 cols]).
// Fragment for 16x16x32: lane l holds B[kt*32 + (l>>4)*8 + i][nt*16 + (l&15)], i=0..7.
__global__ void k_frag(const float* __restrict__ src, unsigned short* __restrict__ dst) {
  int gid = blockIdx.x * 256 + threadIdx.x;  // 32768 total
  int lane = gid & 63, tidx = gid >> 6;
  int nt = tidx & 31, kt = tidx >> 5;
  const float* s = src + (size_t)(nt * 16 + (lane & 15)) * 512 + kt * 32 + (lane >> 4) * 8;
  unsigned short* d = dst + (size_t)gid * 8;
#pragma unroll
  for (int i = 0; i < 8; ++i) d[i] = f2bf(s[i]);
}

// ---------------- big GEMM (P1 and P3) ----------------
// MODE 0 (P1): A fp32 (emb); bias = (t==0 ? bias_t0+z0 : bias_t)
// MODE 1 (P3): A bf16 packed in low half of each fp32 row (h from scan);
//              bias = bout; in-place (A aliases out); t==T-1 rows -> last[]
template <int MODE>
__global__ __launch_bounds__(512) void k_gemm(
    const void* __restrict__ Ain, const unsigned short* __restrict__ fragB,
    float* __restrict__ out, const float* __restrict__ bias_t0,
    const float* __restrict__ bias_t, const float* __restrict__ z0,
    const float* __restrict__ bout, float* __restrict__ last) {
  __shared__ __align__(16) unsigned short a_lds[64 * 512];  // 64KB, XOR-swizzled bf16
  int tid = threadIdx.x;
  long bt0 = (long)blockIdx.x * 64;

  if (MODE == 0) {
    const float* A = (const float*)Ain;
#pragma unroll
    for (int it = 0; it < 16; ++it) {
      int chunk = it * 512 + tid;
      int r = chunk >> 7, c4 = chunk & 127;
      float4 v = ((const float4*)A)[(bt0 + r) * 128 + c4];
      int idx = (r * 512 + c4 * 4) ^ ((r & 7) << 3);
      unsigned short* p = &a_lds[idx];
      p[0] = f2bf(v.x); p[1] = f2bf(v.y); p[2] = f2bf(v.z); p[3] = f2bf(v.w);
    }
  } else {
    const unsigned short* A = (const unsigned short*)Ain;
#pragma unroll
    for (int it = 0; it < 8; ++it) {
      int chunk = it * 512 + tid;           // 4096 chunks of 8 u16
      int r = chunk >> 6, c8 = chunk & 63;
      u16x8 v = *(const u16x8*)(A + (size_t)(bt0 + r) * 1024 + c8 * 8);
      int idx = (r * 512 + c8 * 8) ^ ((r & 7) << 3);
      *(u16x8*)&a_lds[idx] = v;
    }
  }
  __syncthreads();

  int wave = tid >> 6, lane = tid & 63;
  int r0 = (wave & 3) * 16, c0 = (wave >> 2) * 256;
  f32x4 acc[16];
#pragma unroll
  for (int n = 0; n < 16; ++n) acc[n] = (f32x4){0.f, 0.f, 0.f, 0.f};
  int arow = r0 + (lane & 15);

  for (int kt = 0; kt < 16; ++kt) {
    int aidx = (arow * 512 + kt * 32 + (lane >> 4) * 8) ^ ((arow & 7) << 3);
    bf16x8 a = ld_frag(&a_lds[aidx]);
    const unsigned short* bp = fragB + ((size_t)(kt * 32 + (c0 >> 4)) * 64 + lane) * 8;
#pragma unroll
    for (int n = 0; n < 16; ++n) {
      bf16x8 b = ld_frag(bp + (size_t)n * 512);
      acc[n] = __builtin_amdgcn_mfma_f32_16x16x32_bf16(a, b, acc[n], 0, 0, 0);
    }
  }

#pragma unroll
  for (int n = 0; n < 16; ++n) {
    int col = c0 + n * 16 + (lane & 15);
#pragma unroll
    for (int reg = 0; reg < 4; ++reg) {
      long row = bt0 + r0 + (lane >> 4) * 4 + reg;
      float v = acc[n][reg];
      if (MODE == 0) {
        int t = (int)(row & (NT - 1));
        long b = row >> 11;
        v += (t == 0) ? (bias_t0[col] + z0[b * NH + col]) : bias_t[col];
      } else {
        v += bout[col];
      }
      out[row * 512 + col] = v;
      if (MODE == 1 && ((row & (NT - 1)) == NT - 1)) last[(row >> 11) * 512 + col] = v;
    }
  }
}

// ---------------- sequential scan ----------------
// grid 4 x 512 threads; WG w owns batches [16w, 16w+16). No inter-WG sync.
// h state: LDS bf16 [2][16][512], XOR-swizzled. h also stored bf16 to the low
// half of buf's fp32 rows (P3 reads it from there).
__global__ __launch_bounds__(512, 2) void k_scan(float* __restrict__ buf,
                                                 const unsigned short* __restrict__ fragWc) {
  __shared__ __align__(16) unsigned short h_lds[2][16 * 512];  // 32KB
  unsigned short* hbuf = (unsigned short*)buf;
  const int tid = threadIdx.x;
  const int b0 = blockIdx.x * 16;
  const int wave = tid >> 6, lane = tid & 63;
  const int arow = lane & 15, bb = lane >> 4;
  const int c0 = wave * 64;
  const int swz = (arow & 7) << 3;

  // Wc fragments kt=0..7: load once, PIN in VGPRs via opaque asm (the compiler
  // otherwise rematerializes these loop-invariant loads each step — R3's bug:
  // VGPR_Count stayed 128 and the full 512KB streamed from L2 every step).
  const unsigned short* bW = fragWc + ((size_t)(wave * 4) * 64 + lane) * 8;
  f32x4 br[8][4];
#pragma unroll
  for (int kt = 0; kt < 8; ++kt)
#pragma unroll
    for (int n = 0; n < 4; ++n) br[kt][n] = ld_frag4(bW + (size_t)(kt * 32 + n) * 512);
#pragma unroll
  for (int kt = 0; kt < 8; ++kt)
#pragma unroll
    for (int n = 0; n < 4; ++n) asm volatile("" : "+v"(br[kt][n]));

  // ---- t = 0 : h0 = tanh(pre0). Read-all / barrier / write (bf16 writes alias
  // other threads' fp32 reads, so the phases must be separated).
  float v0[16];
#pragma unroll
  for (int i = 0; i < 16; ++i) v0[i] = buf[(size_t)(b0 + i) * TH + tid];
  __syncthreads();
#pragma unroll
  for (int i = 0; i < 16; ++i) {
    float h = fast_tanh(v0[i]);
    unsigned short hb = f2bf(h);
    hbuf[(size_t)(b0 + i) * (size_t)NT * 1024 + tid] = hb;
    h_lds[0][(i * 512 + tid) ^ ((i & 7) << 3)] = hb;
  }

  // per-lane global pointers at the t=1 row
  const float* pPre[4];
  unsigned short* pSt[4];
#pragma unroll
  for (int r = 0; r < 4; ++r) {
    int b = b0 + bb * 4 + r;
    pPre[r] = buf + (size_t)b * TH + 512 + c0 + arow;
    pSt[r]  = hbuf + (size_t)b * (size_t)NT * 1024 + 1024 + c0 + arow;
  }

  // preload pre(t=1)
  float pre[16];
#pragma unroll
  for (int n = 0; n < 4; ++n)
#pragma unroll
    for (int r = 0; r < 4; ++r) pre[n * 4 + r] = pPre[r][n * 16];

  __syncthreads();  // h_lds[0] visible to all waves

#define AIDX(k) ((arow * 512 + (k) * 32 + bb * 8) ^ swz)

#pragma unroll 1
  for (int t = 1; t < NT; ++t) {
    // 1) issue streaming-B prefetch for kt=8,9 first (consumed mid-step)
    bf16x8 p0[4], p1[4];
#pragma unroll
    for (int n = 0; n < 4; ++n) p0[n] = ld_frag(bW + (size_t)(8 * 32 + n) * 512);
#pragma unroll
    for (int n = 0; n < 4; ++n) p1[n] = ld_frag(bW + (size_t)(9 * 32 + n) * 512);

    // 2) consume pre into acc, then immediately issue pre(t+1) loads (consumed
    //    next step; raw barrier won't drain them)
    f32x4 acc[4];
#pragma unroll
    for (int n = 0; n < 4; ++n)
#pragma unroll
      for (int r = 0; r < 4; ++r) acc[n][r] = pre[n * 4 + r];

    if (t < NT - 1) {
#pragma unroll
      for (int r = 0; r < 4; ++r) pPre[r] += 512;
#pragma unroll
      for (int n = 0; n < 4; ++n)
#pragma unroll
        for (int r = 0; r < 4; ++r) pre[n * 4 + r] = pPre[r][n * 16];
    }

    const unsigned short* hs = h_lds[(t - 1) & 1];

    // persistent half: kt = 0..7, B resident in registers
#pragma unroll
    for (int kt = 0; kt < 8; ++kt) {
      bf16x8 a = ld_frag(hs + AIDX(kt));
#pragma unroll
      for (int n = 0; n < 4; ++n)
        acc[n] = __builtin_amdgcn_mfma_f32_16x16x32_bf16(
            a, __builtin_bit_cast(bf16x8, br[kt][n]), acc[n], 0, 0, 0);
    }

    // streamed half: kt = 8..15, rotating 2-group prefetch
#pragma unroll
    for (int kk = 8; kk < 16; kk += 2) {
      bf16x8 a0 = ld_frag(hs + AIDX(kk));
#pragma unroll
      for (int n = 0; n < 4; ++n)
        acc[n] = __builtin_amdgcn_mfma_f32_16x16x32_bf16(a0, p0[n], acc[n], 0, 0, 0);
      if (kk + 2 < 16) {
#pragma unroll
        for (int n = 0; n < 4; ++n) p0[n] = ld_frag(bW + (size_t)((kk + 2) * 32 + n) * 512);
      }
      bf16x8 a1 = ld_frag(hs + AIDX(kk + 1));
#pragma unroll
      for (int n = 0; n < 4; ++n)
        acc[n] = __builtin_amdgcn_mfma_f32_16x16x32_bf16(a1, p1[n], acc[n], 0, 0, 0);
      if (kk + 3 < 16) {
#pragma unroll
        for (int n = 0; n < 4; ++n) p1[n] = ld_frag(bW + (size_t)((kk + 3) * 32 + n) * 512);
      }
    }

    // epilogue: tanh -> bf16 h -> global (P3 input) + LDS (next step's A)
    unsigned short* hdst = h_lds[t & 1];
#pragma unroll
    for (int n = 0; n < 4; ++n)
#pragma unroll
      for (int r = 0; r < 4; ++r) {
        int b = bb * 4 + r;
        float h = fast_tanh(acc[n][r]);
        unsigned short hb = f2bf(h);
        pSt[r][n * 16] = hb;
        hdst[(b * 512 + c0 + n * 16 + arow) ^ ((b & 7) << 3)] = hb;
      }
#pragma unroll
    for (int r = 0; r < 4; ++r) pSt[r] += 1024;

    // lgkm-only drain + raw barrier: LDS h-exchange synced, global loads/stores
    // stay in flight across the step boundary (no vmcnt(0) drain).
    asm volatile("s_waitcnt lgkmcnt(0)" ::: "memory");
    __builtin_amdgcn_s_barrier();
    asm volatile("" ::: "memory");
  }
#undef AIDX
}

// ---------------- launch ----------------
extern "C" void kernel_launch(void* const* d_in, const int* in_sizes, int n_in,
                              void* d_out, int out_size, void* d_ws, size_t ws_size,
                              hipStream_t stream) {
  const float* emb  = (const float*)d_in[0];
  const float* ll   = (const float*)d_in[1];
  const float* Whx  = (const float*)d_in[2];
  const float* bhx  = (const float*)d_in[3];
  const float* Wyh  = (const float*)d_in[4];
  const float* byh  = (const float*)d_in[5];
  const float* Wout = (const float*)d_in[6];
  const float* bout = (const float*)d_in[7];

  float* buf  = (float*)d_out;                       // [B*T, 512] pre -> h -> y (in place)
  float* last = buf + (size_t)NB * NT * NO;          // [B, O] tail

  char* ws = (char*)d_ws;                            // ~2.7 MB used
  unsigned short* fragWhx  = (unsigned short*)ws;                         // 512KB
  unsigned short* fragWc   = (unsigned short*)(ws + (512 * 512 * 2));     // 512KB
  unsigned short* fragWout = (unsigned short*)(ws + 2 * (512 * 512 * 2)); // 512KB
  float* z0      = (float*)(ws + 3 * (512 * 512 * 2));                    // 128KB
  float* bias_t0 = z0 + NB * NH;
  float* bias_t  = bias_t0 + NH;
  float* Wc_f32  = bias_t + NH;                                           // 1MB

  k_bias<<<1, 512, 0, stream>>>(Wyh, bout, bhx, byh, bias_t0, bias_t);
  k_z0<<<64, 512, 0, stream>>>(ll, Wyh, z0);
  k_wc<<<512, 512, 0, stream>>>(Wyh, Wout, Wc_f32);
  k_frag<<<128, 256, 0, stream>>>(Whx, fragWhx);     // Bm[d][j] = Whx[j][d]
  k_frag<<<128, 256, 0, stream>>>(Wc_f32, fragWc);   // Bm[k][j] = Wc[j][k]
  k_frag<<<128, 256, 0, stream>>>(Wout, fragWout);   // Bm[k][o] = Wout[o][k]

  // P1: pre = emb @ Whx^T + biases (t==0 rows get z0)
  k_gemm<0><<<2048, 512, 0, stream>>>(emb, fragWhx, buf, bias_t0, bias_t, z0, bout, last);
  // P2: sequential scan, h (bf16) in place over pre
  k_scan<<<4, 512, 0, stream>>>(buf, fragWc);
  // P3: y = h @ Wout^T + bout, in place over h; also fills `last`
  k_gemm<1><<<2048, 512, 0, stream>>>(buf, fragWout, buf, bias_t0, bias_t, z0, bout, last);
}

// Round 6
// 8361.682 us; speedup vs baseline: 2.3212x; 1.7648x over previous
//
#include <hip/hip_runtime.h>
#include <hip/hip_bf16.h>

// Jordan RNN restructured:
//   Wc = Wyh @ Wout  [H,H]
//   pre[b,t,:] = emb@Whx^T + bhx + byh + (t==0 ? last_logits@Wyh^T : Wyh@bout)
//   scan: h_t = tanh(pre_t + h_{t-1} @ Wc^T)     (per-batch independent!)
//   y_t  = h_t @ Wout^T + bout                    (time-parallel epilogue GEMM)
// Scan Wc placement per CU (512KB total, bf16 fragments):
//   kt 0..6   pinned in VGPRs (112 regs/wave, opaque-asm pinned)
//   kt 7..12  streamed from L2, 3-buffer rotation, reissue-at-consume
//             (stable mapping since 6 % 3 == 0; prefetch distance 3 groups)
//   kt 13..15 LDS-resident (96KB, filled once)
// VMEM issue order per step: [B reissues] -> [pre(t+1)] -> [h stores], so
// in-order vmcnt waits on B-consumes never chain behind slow pre loads.

#define NB 64
#define NT 2048
#define ND 512
#define NH 512
#define NO 512
#define TH (NT * NH)

typedef float f32x4 __attribute__((ext_vector_type(4)));
typedef __bf16 bf16x8 __attribute__((ext_vector_type(8)));
typedef unsigned short u16x8 __attribute__((ext_vector_type(8)));

__device__ __forceinline__ unsigned short f2bf(float x) {
  unsigned u = __builtin_bit_cast(unsigned, x);
  u += 0x7FFFu + ((u >> 16) & 1u);               // RNE
  return (unsigned short)(u >> 16);
}
__device__ __forceinline__ bf16x8 ld_frag(const unsigned short* p) {
  u16x8 r = *(const u16x8*)p;
  return __builtin_bit_cast(bf16x8, r);
}
__device__ __forceinline__ f32x4 ld_frag4(const unsigned short* p) {
  return *(const f32x4*)p;
}
// tanh via hardware exp2/rcp: abs err ~1e-6, inf-safe.
__device__ __forceinline__ float fast_tanh(float x) {
  float ax = __builtin_fabsf(x);
  float e = __builtin_amdgcn_exp2f(ax * 2.8853900817779268f);  // e^(2|x|)
  float r = 1.0f - 2.0f * __builtin_amdgcn_rcpf(e + 1.0f);
  return __builtin_copysignf(r, x);
}

// ---------------- prep kernels ----------------

__global__ void k_bias(const float* __restrict__ Wyh, const float* __restrict__ bout,
                       const float* __restrict__ bhx, const float* __restrict__ byh,
                       float* bias_t0, float* bias_t) {
  int j = threadIdx.x;
  const float* row = Wyh + j * NO;
  float acc = 0.f;
  for (int o = 0; o < NO; ++o) acc += row[o] * bout[o];
  bias_t0[j] = bhx[j] + byh[j];
  bias_t[j]  = bhx[j] + byh[j] + acc;
}

__global__ void k_z0(const float* __restrict__ ll, const float* __restrict__ Wyh,
                     float* z0) {
  int b = blockIdx.x, j = threadIdx.x;
  const float* row = Wyh + j * NO;
  const float* lr = ll + b * NO;
  float acc = 0.f;
  for (int o = 0; o < NO; ++o) acc += lr[o] * row[o];
  z0[b * NH + j] = acc;
}

__global__ void k_wc(const float* __restrict__ Wyh, const float* __restrict__ Wout,
                     float* Wc) {
  int j = blockIdx.x, k = threadIdx.x;
  float acc = 0.f;
  for (int o = 0; o < NO; ++o) acc += Wyh[j * NO + o] * Wout[o * NH + k];
  Wc[j * NH + k] = acc;
}

// Build MFMA B-operand fragments for Bm = src^T (src is [N=512 rows][K=512 cols]).
// Fragment for 16x16x32: lane l holds B[kt*32 + (l>>4)*8 + i][nt*16 + (l&15)], i=0..7.
__global__ void k_frag(const float* __restrict__ src, unsigned short* __restrict__ dst) {
  int gid = blockIdx.x * 256 + threadIdx.x;  // 32768 total
  int lane = gid & 63, tidx = gid >> 6;
  int nt = tidx & 31, kt = tidx >> 5;
  const float* s = src + (size_t)(nt * 16 + (lane & 15)) * 512 + kt * 32 + (lane >> 4) * 8;
  unsigned short* d = dst + (size_t)gid * 8;
#pragma unroll
  for (int i = 0; i < 8; ++i) d[i] = f2bf(s[i]);
}

// ---------------- big GEMM (P1 and P3) ----------------
// MODE 0 (P1): A fp32 (emb); bias = (t==0 ? bias_t0+z0 : bias_t)
// MODE 1 (P3): A bf16 packed in low half of each fp32 row (h from scan);
//              bias = bout; in-place (A aliases out); t==T-1 rows -> last[]
template <int MODE>
__global__ __launch_bounds__(512) void k_gemm(
    const void* __restrict__ Ain, const unsigned short* __restrict__ fragB,
    float* __restrict__ out, const float* __restrict__ bias_t0,
    const float* __restrict__ bias_t, const float* __restrict__ z0,
    const float* __restrict__ bout, float* __restrict__ last) {
  __shared__ __align__(16) unsigned short a_lds[64 * 512];  // 64KB, XOR-swizzled bf16
  int tid = threadIdx.x;
  long bt0 = (long)blockIdx.x * 64;

  if (MODE == 0) {
    const float* A = (const float*)Ain;
#pragma unroll
    for (int it = 0; it < 16; ++it) {
      int chunk = it * 512 + tid;
      int r = chunk >> 7, c4 = chunk & 127;
      float4 v = ((const float4*)A)[(bt0 + r) * 128 + c4];
      int idx = (r * 512 + c4 * 4) ^ ((r & 7) << 3);
      unsigned short* p = &a_lds[idx];
      p[0] = f2bf(v.x); p[1] = f2bf(v.y); p[2] = f2bf(v.z); p[3] = f2bf(v.w);
    }
  } else {
    const unsigned short* A = (const unsigned short*)Ain;
#pragma unroll
    for (int it = 0; it < 8; ++it) {
      int chunk = it * 512 + tid;           // 4096 chunks of 8 u16
      int r = chunk >> 6, c8 = chunk & 63;
      u16x8 v = *(const u16x8*)(A + (size_t)(bt0 + r) * 1024 + c8 * 8);
      int idx = (r * 512 + c8 * 8) ^ ((r & 7) << 3);
      *(u16x8*)&a_lds[idx] = v;
    }
  }
  __syncthreads();

  int wave = tid >> 6, lane = tid & 63;
  int r0 = (wave & 3) * 16, c0 = (wave >> 2) * 256;
  f32x4 acc[16];
#pragma unroll
  for (int n = 0; n < 16; ++n) acc[n] = (f32x4){0.f, 0.f, 0.f, 0.f};
  int arow = r0 + (lane & 15);

  for (int kt = 0; kt < 16; ++kt) {
    int aidx = (arow * 512 + kt * 32 + (lane >> 4) * 8) ^ ((arow & 7) << 3);
    bf16x8 a = ld_frag(&a_lds[aidx]);
    const unsigned short* bp = fragB + ((size_t)(kt * 32 + (c0 >> 4)) * 64 + lane) * 8;
#pragma unroll
    for (int n = 0; n < 16; ++n) {
      bf16x8 b = ld_frag(bp + (size_t)n * 512);
      acc[n] = __builtin_amdgcn_mfma_f32_16x16x32_bf16(a, b, acc[n], 0, 0, 0);
    }
  }

#pragma unroll
  for (int n = 0; n < 16; ++n) {
    int col = c0 + n * 16 + (lane & 15);
#pragma unroll
    for (int reg = 0; reg < 4; ++reg) {
      long row = bt0 + r0 + (lane >> 4) * 4 + reg;
      float v = acc[n][reg];
      if (MODE == 0) {
        int t = (int)(row & (NT - 1));
        long b = row >> 11;
        v += (t == 0) ? (bias_t0[col] + z0[b * NH + col]) : bias_t[col];
      } else {
        v += bout[col];
      }
      out[row * 512 + col] = v;
      if (MODE == 1 && ((row & (NT - 1)) == NT - 1)) last[(row >> 11) * 512 + col] = v;
    }
  }
}

// ---------------- sequential scan ----------------
// grid 4 x 512 threads; WG w owns batches [16w, 16w+16). No inter-WG sync.
// h: LDS bf16 [2][16][512] XOR-swizzled; also stored bf16 to global (P3 input).
__global__ __launch_bounds__(512, 2) void k_scan(float* __restrict__ buf,
                                                 const unsigned short* __restrict__ fragWc) {
  __shared__ __align__(16) unsigned short h_lds[2][16 * 512];   // 32KB
  __shared__ __align__(16) unsigned short wc_lds[8 * 12 * 512]; // 96KB: 8 waves x (3kt x 4n) frags
  unsigned short* hbuf = (unsigned short*)buf;
  const int tid = threadIdx.x;
  const int b0 = blockIdx.x * 16;
  const int wave = tid >> 6, lane = tid & 63;
  const int arow = lane & 15, bb = lane >> 4;
  const int c0 = wave * 64;
  const int swz = (arow & 7) << 3;

  const unsigned short* bW = fragWc + ((size_t)(wave * 4) * 64 + lane) * 8;

  // ---- Wc kt=13..15 -> LDS (once) ----
#pragma unroll
  for (int g = 0; g < 3; ++g)
#pragma unroll
    for (int n = 0; n < 4; ++n) {
      f32x4 v = ld_frag4(bW + (size_t)((13 + g) * 32 + n) * 512);
      *(f32x4*)&wc_lds[(size_t)((wave * 3 + g) * 4 + n) * 512 + lane * 8] = v;
    }

  // ---- Wc kt=0..6 -> VGPRs, pinned via opaque asm ----
  f32x4 br[7][4];
#pragma unroll
  for (int kt = 0; kt < 7; ++kt)
#pragma unroll
    for (int n = 0; n < 4; ++n) br[kt][n] = ld_frag4(bW + (size_t)(kt * 32 + n) * 512);
#pragma unroll
  for (int kt = 0; kt < 7; ++kt)
#pragma unroll
    for (int n = 0; n < 4; ++n) asm volatile("" : "+v"(br[kt][n]));

  // ---- t = 0 : h0 = tanh(pre0). Read-all / barrier / write. ----
  float v0[16];
#pragma unroll
  for (int i = 0; i < 16; ++i) v0[i] = buf[(size_t)(b0 + i) * TH + tid];
  __syncthreads();
#pragma unroll
  for (int i = 0; i < 16; ++i) {
    float h = fast_tanh(v0[i]);
    unsigned short hb = f2bf(h);
    hbuf[(size_t)(b0 + i) * (size_t)NT * 1024 + tid] = hb;
    h_lds[0][(i * 512 + tid) ^ ((i & 7) << 3)] = hb;
  }

  // per-lane global pointers at the t=1 row
  const float* pPre[4];
  unsigned short* pSt[4];
#pragma unroll
  for (int r = 0; r < 4; ++r) {
    int b = b0 + bb * 4 + r;
    pPre[r] = buf + (size_t)b * TH + 512 + c0 + arow;
    pSt[r]  = hbuf + (size_t)b * (size_t)NT * 1024 + 1024 + c0 + arow;
  }

  // preload pre(t=1)
  float pre[16];
#pragma unroll
  for (int n = 0; n < 4; ++n)
#pragma unroll
    for (int r = 0; r < 4; ++r) pre[n * 4 + r] = pPre[r][n * 16];

  // stream prologue: q0<-kt7, q1<-kt8, q2<-kt9
  bf16x8 q0[4], q1[4], q2[4];
#pragma unroll
  for (int n = 0; n < 4; ++n) q0[n] = ld_frag(bW + (size_t)(7 * 32 + n) * 512);
#pragma unroll
  for (int n = 0; n < 4; ++n) q1[n] = ld_frag(bW + (size_t)(8 * 32 + n) * 512);
#pragma unroll
  for (int n = 0; n < 4; ++n) q2[n] = ld_frag(bW + (size_t)(9 * 32 + n) * 512);

  __syncthreads();  // h_lds[0] + wc_lds visible to all waves

#define AIDX(k) ((arow * 512 + (k) * 32 + bb * 8) ^ swz)
// consume buffer Q against h-fragment kt=KT, then reissue Q <- group RKT
#define STREAM_STEP(Q, KT, RKT)                                                     \
  {                                                                                 \
    bf16x8 a = ld_frag(hs + AIDX(KT));                                              \
    _Pragma("unroll") for (int n = 0; n < 4; ++n)                                   \
        acc[n] = __builtin_amdgcn_mfma_f32_16x16x32_bf16(a, Q[n], acc[n], 0, 0, 0); \
    _Pragma("unroll") for (int n = 0; n < 4; ++n)                                   \
        Q[n] = ld_frag(bWs + (size_t)((RKT) * 32 + n) * 512);                       \
  }

#pragma unroll 1
  for (int t = 1; t < NT; ++t) {
    // launder the stream base pointer so LICM can't hoist the reissue loads
    const unsigned short* bWs = bW;
    asm volatile("" : "+v"(bWs));

    f32x4 acc[4];
#pragma unroll
    for (int n = 0; n < 4; ++n)
#pragma unroll
      for (int r = 0; r < 4; ++r) acc[n][r] = pre[n * 4 + r];

    const unsigned short* hs = h_lds[(t - 1) & 1];

    // pinned phase: kt = 0..6 (B resident; runs while stream loads land)
#pragma unroll
    for (int kt = 0; kt < 7; ++kt) {
      bf16x8 a = ld_frag(hs + AIDX(kt));
#pragma unroll
      for (int n = 0; n < 4; ++n)
        acc[n] = __builtin_amdgcn_mfma_f32_16x16x32_bf16(
            a, __builtin_bit_cast(bf16x8, br[kt][n]), acc[n], 0, 0, 0);
    }

    // streamed phase: kt = 7..12, stable 3-buffer rotation, reissue-at-consume
    STREAM_STEP(q0, 7, 10)
    STREAM_STEP(q1, 8, 11)
    STREAM_STEP(q2, 9, 12)
    STREAM_STEP(q0, 10, 7)   // reissues here land for step t+1
    STREAM_STEP(q1, 11, 8)
    STREAM_STEP(q2, 12, 9)

    // LDS-resident phase: kt = 13..15
#pragma unroll
    for (int g = 0; g < 3; ++g) {
      bf16x8 a = ld_frag(hs + AIDX(13 + g));
#pragma unroll
      for (int n = 0; n < 4; ++n) {
        bf16x8 b = ld_frag(&wc_lds[(size_t)((wave * 3 + g) * 4 + n) * 512 + lane * 8]);
        acc[n] = __builtin_amdgcn_mfma_f32_16x16x32_bf16(a, b, acc[n], 0, 0, 0);
      }
    }

    // pre(t+1): issued AFTER all B loads of this step (in-order vmcnt safety)
    if (t < NT - 1) {
#pragma unroll
      for (int r = 0; r < 4; ++r) pPre[r] += 512;
#pragma unroll
      for (int n = 0; n < 4; ++n)
#pragma unroll
        for (int r = 0; r < 4; ++r) pre[n * 4 + r] = pPre[r][n * 16];
    }

    // epilogue: tanh -> bf16 h -> global (P3 input) + LDS (next step's A)
    unsigned short* hdst = h_lds[t & 1];
#pragma unroll
    for (int n = 0; n < 4; ++n)
#pragma unroll
      for (int r = 0; r < 4; ++r) {
        int b = bb * 4 + r;
        float h = fast_tanh(acc[n][r]);
        unsigned short hb = f2bf(h);
        pSt[r][n * 16] = hb;
        hdst[(b * 512 + c0 + n * 16 + arow) ^ ((b & 7) << 3)] = hb;
      }
#pragma unroll
    for (int r = 0; r < 4; ++r) pSt[r] += 1024;

    // lgkm-only drain + raw barrier: LDS h-exchange synced; global loads/stores
    // (stream reissues, pre, h-stores) stay in flight across the boundary.
    asm volatile("s_waitcnt lgkmcnt(0)" ::: "memory");
    __builtin_amdgcn_s_barrier();
    asm volatile("" ::: "memory");
  }
#undef STREAM_STEP
#undef AIDX
}

// ---------------- launch ----------------
extern "C" void kernel_launch(void* const* d_in, const int* in_sizes, int n_in,
                              void* d_out, int out_size, void* d_ws, size_t ws_size,
                              hipStream_t stream) {
  const float* emb  = (const float*)d_in[0];
  const float* ll   = (const float*)d_in[1];
  const float* Whx  = (const float*)d_in[2];
  const float* bhx  = (const float*)d_in[3];
  const float* Wyh  = (const float*)d_in[4];
  const float* byh  = (const float*)d_in[5];
  const float* Wout = (const float*)d_in[6];
  const float* bout = (const float*)d_in[7];

  float* buf  = (float*)d_out;                       // [B*T, 512] pre -> h -> y (in place)
  float* last = buf + (size_t)NB * NT * NO;          // [B, O] tail

  char* ws = (char*)d_ws;                            // ~2.7 MB used
  unsigned short* fragWhx  = (unsigned short*)ws;                         // 512KB
  unsigned short* fragWc   = (unsigned short*)(ws + (512 * 512 * 2));     // 512KB
  unsigned short* fragWout = (unsigned short*)(ws + 2 * (512 * 512 * 2)); // 512KB
  float* z0      = (float*)(ws + 3 * (512 * 512 * 2));                    // 128KB
  float* bias_t0 = z0 + NB * NH;
  float* bias_t  = bias_t0 + NH;
  float* Wc_f32  = bias_t + NH;                                           // 1MB

  k_bias<<<1, 512, 0, stream>>>(Wyh, bout, bhx, byh, bias_t0, bias_t);
  k_z0<<<64, 512, 0, stream>>>(ll, Wyh, z0);
  k_wc<<<512, 512, 0, stream>>>(Wyh, Wout, Wc_f32);
  k_frag<<<128, 256, 0, stream>>>(Whx, fragWhx);     // Bm[d][j] = Whx[j][d]
  k_frag<<<128, 256, 0, stream>>>(Wc_f32, fragWc);   // Bm[k][j] = Wc[j][k]
  k_frag<<<128, 256, 0, stream>>>(Wout, fragWout);   // Bm[k][o] = Wout[o][k]

  // P1: pre = emb @ Whx^T + biases (t==0 rows get z0)
  k_gemm<0><<<2048, 512, 0, stream>>>(emb, fragWhx, buf, bias_t0, bias_t, z0, bout, last);
  // P2: sequential scan, h (bf16) in place over pre
  k_scan<<<4, 512, 0, stream>>>(buf, fragWc);
  // P3: y = h @ Wout^T + bout, in place over h; also fills `last`
  k_gemm<1><<<2048, 512, 0, stream>>>(buf, fragWout, buf, bias_t0, bias_t, z0, bout, last);
}